// Round 1
// baseline (79.957 us; speedup 1.0000x reference)
//
#include <hip/hip_runtime.h>

// CapsuleLayer: u_hat[b,c,r,o] = sum_i W[c,r,o,i] * x[b,r,i]; out = squash(u_hat) over o.
// B=256, C=10, R=1152, I=8, O=16. fp32 in/out. Memory-bound on the 189 MB output write.

#define NB 256
#define NC 10
#define NR 1152
#define NI 8
#define NO 16
#define B_PER_BLOCK 8

__global__ __launch_bounds__(256) void capsule_squash_kernel(
    const float* __restrict__ x,   // [B, R, I]
    const float* __restrict__ W,   // [C, R, O, I]
    float* __restrict__ out)       // [B, C, R, O]
{
    const int tid = threadIdx.x;
    const int o   = tid & 15;        // lane within 16-group = output channel
    const int g   = tid >> 4;        // group 0..15 within block
    const int w   = blockIdx.x * 16 + g;   // w = c*NR + r, in [0, NC*NR)
    const int c   = w / NR;
    const int r   = w - c * NR;

    // Load this thread's W row once: W[(w*NO + o)*NI .. +8)
    const float4* wp = reinterpret_cast<const float4*>(W + (size_t)(w * NO + o) * NI);
    const float4 w0 = wp[0];
    const float4 w1 = wp[1];

    const int b0 = blockIdx.y * B_PER_BLOCK;

    #pragma unroll
    for (int j = 0; j < B_PER_BLOCK; ++j) {
        const int b = b0 + j;
        const float4* xp = reinterpret_cast<const float4*>(x + (size_t)(b * NR + r) * NI);
        const float4 x0 = xp[0];
        const float4 x1 = xp[1];

        // u_hat = dot(W[c,r,o,:], x[b,r,:])
        float u = w0.x * x0.x + w0.y * x0.y + w0.z * x0.z + w0.w * x0.w
                + w1.x * x1.x + w1.y * x1.y + w1.z * x1.z + w1.w * x1.w;

        // sq_norm over the 16-lane o-group (masks 1,2,4,8 stay within the group)
        float sq = u * u;
        sq += __shfl_xor(sq, 1);
        sq += __shfl_xor(sq, 2);
        sq += __shfl_xor(sq, 4);
        sq += __shfl_xor(sq, 8);

        // squash: u * (sq/(1+sq)) / sqrt(sq + 1e-9)
        const float scale = sq / (1.0f + sq);
        const float val   = u * scale / sqrtf(sq + 1e-9f);

        out[((size_t)b * (NC * NR) + w) * NO + o] = val;
    }
}

extern "C" void kernel_launch(void* const* d_in, const int* in_sizes, int n_in,
                              void* d_out, int out_size, void* d_ws, size_t ws_size,
                              hipStream_t stream) {
    const float* x = (const float*)d_in[0];   // [256, 1152, 8]
    const float* W = (const float*)d_in[1];   // [1, 10, 1152, 16, 8]
    float* out = (float*)d_out;               // [256, 10, 1152, 16]

    dim3 grid(NC * NR / 16, NB / B_PER_BLOCK);  // (720, 32)
    dim3 block(256);
    capsule_squash_kernel<<<grid, block, 0, stream>>>(x, W, out);
}

// Round 2
// 49.258 us; speedup vs baseline: 1.6232x; 1.6232x over previous
//
#include <hip/hip_runtime.h>

// CapsuleLayer: u_hat[b,c,r,o] = sum_i W[c,r,o,i] * x[b,r,i]; out = squash(u_hat) over o.
// B=256, C=10, R=1152, I=8, O=16. fp32. Memory-bound target: 188.7 MB out write ≈ 30 us.
//
// Layout: 4 lanes per (c,r) pair; each lane owns o = l4*4..l4*4+3 (4 outputs).
//  - store is one dwordx4 per lane; wave's 64 lanes cover 1 KB contiguous.
//  - sq_norm reduce = 2 shfl_xor (within the 4-lane group) instead of 4.
//  - squash via v_rcp_f32 + v_rsq_f32 (single-instr approx; threshold 1.86e-2 >> 1e-6 err).

#define NB 256
#define NC 10
#define NR 1152
#define NI 8
#define NO 16
#define B_PER_BLOCK 8

__global__ __launch_bounds__(256) void capsule_squash_kernel(
    const float* __restrict__ x,   // [B, R, I]
    const float* __restrict__ W,   // [C, R, O, I]
    float* __restrict__ out)       // [B, C, R, O]
{
    const int tid = threadIdx.x;
    const int l4  = tid & 3;          // o-subgroup: this lane's o = l4*4 + 0..3
    const int g   = tid >> 2;         // group 0..63 in block
    const int w   = blockIdx.x * 64 + g;   // w = c*NR + r in [0, NC*NR)
    const int r   = w % NR;

    // This lane's 4 W rows: W[(w*NO + l4*4 + k)*NI + i], k=0..3, i=0..7  -> 8 float4
    const float4* wp = reinterpret_cast<const float4*>(W + (size_t)(w * NO + l4 * 4) * NI);
    float4 wr[8];
    #pragma unroll
    for (int k = 0; k < 8; ++k) wr[k] = wp[k];

    const int b0 = blockIdx.y * B_PER_BLOCK;
    const float4* xp = reinterpret_cast<const float4*>(x + ((size_t)b0 * NR + r) * NI);
    float4*       op = reinterpret_cast<float4*>(out + ((size_t)b0 * (NC * NR) + w) * NO + l4 * 4);

    #pragma unroll
    for (int j = 0; j < B_PER_BLOCK; ++j) {
        const float4 x0 = xp[0];
        const float4 x1 = xp[1];
        xp += (NR * NI) / 4;          // next b: 1152*8 floats

        float u[4];
        #pragma unroll
        for (int k = 0; k < 4; ++k) {
            u[k] = wr[2*k].x   * x0.x + wr[2*k].y   * x0.y + wr[2*k].z   * x0.z + wr[2*k].w   * x0.w
                 + wr[2*k+1].x * x1.x + wr[2*k+1].y * x1.y + wr[2*k+1].z * x1.z + wr[2*k+1].w * x1.w;
        }

        // sq_norm over 16 o: 4 local + 2-step shfl reduce across the 4-lane group
        float sq = u[0]*u[0] + u[1]*u[1] + u[2]*u[2] + u[3]*u[3];
        sq += __shfl_xor(sq, 1);
        sq += __shfl_xor(sq, 2);

        // factor = sq / ((1+sq) * sqrt(sq+1e-9)) via fast rcp/rsq
        const float f = sq * __builtin_amdgcn_rcpf(1.0f + sq)
                           * __builtin_amdgcn_rsqf(sq + 1e-9f);

        float4 v;
        v.x = u[0] * f; v.y = u[1] * f; v.z = u[2] * f; v.w = u[3] * f;
        *op = v;
        op += (NC * NR * NO) / 4;     // next b: 11520*16 floats
    }
}

extern "C" void kernel_launch(void* const* d_in, const int* in_sizes, int n_in,
                              void* d_out, int out_size, void* d_ws, size_t ws_size,
                              hipStream_t stream) {
    const float* x = (const float*)d_in[0];   // [256, 1152, 8]
    const float* W = (const float*)d_in[1];   // [1, 10, 1152, 16, 8]
    float* out = (float*)d_out;               // [256, 10, 1152, 16]

    dim3 grid(NC * NR / 64, NB / B_PER_BLOCK);  // (180, 32)
    dim3 block(256);
    capsule_squash_kernel<<<grid, block, 0, stream>>>(x, W, out);
}

// Round 4
// 41.288 us; speedup vs baseline: 1.9365x; 1.1930x over previous
//
#include <hip/hip_runtime.h>

// CapsuleLayer: u_hat[b,c,r,o] = sum_i W[c,r,o,i] * x[b,r,i]; out = squash(u_hat) over o.
// B=256, C=10, R=1152, I=8, O=16. fp32. Roofline: 188.7 MB out write + ~15 MB fetch ≈ 30 us.
//
// Layout: 4 lanes per (c,r); lane owns o = l4*4..+3. dwordx4 NT stores (1 KB/wave contig).
// Reduce via DPP quad_perm (full-rate VALU, no LDS pipe). B_PER_BLOCK=16 halves W L2 refetch.
// __launch_bounds__(256,6) caps VGPR ~85 -> 6 waves/SIMD for latency hiding.

#define NB 256
#define NC 10
#define NR 1152
#define NI 8
#define NO 16
#define B_PER_BLOCK 16

typedef float f32x4 __attribute__((ext_vector_type(4)));

template <int CTRL>
__device__ __forceinline__ float dpp_quad(float v) {
    int i = __builtin_bit_cast(int, v);
    int r = __builtin_amdgcn_update_dpp(i, i, CTRL, 0xF, 0xF, true);
    return __builtin_bit_cast(float, r);
}

__global__ __launch_bounds__(256, 6) void capsule_squash_kernel(
    const float* __restrict__ x,   // [B, R, I]
    const float* __restrict__ W,   // [C, R, O, I]
    float* __restrict__ out)       // [B, C, R, O]
{
    const int tid = threadIdx.x;
    const int l4  = tid & 3;          // lane's o = l4*4 + 0..3
    const int g   = tid >> 2;         // group 0..63 in block
    const int w   = blockIdx.x * 64 + g;   // w = c*NR + r
    const int r   = w % NR;

    // This lane's 4 W rows: 8 float4 (32 VGPRs), loaded once, used for 16 batches.
    const f32x4* wp = reinterpret_cast<const f32x4*>(W + (size_t)(w * NO + l4 * 4) * NI);
    f32x4 wr[8];
    #pragma unroll
    for (int k = 0; k < 8; ++k) wr[k] = wp[k];

    const int b0 = blockIdx.y * B_PER_BLOCK;
    const f32x4* xp = reinterpret_cast<const f32x4*>(x + ((size_t)b0 * NR + r) * NI);
    f32x4*       op = reinterpret_cast<f32x4*>(out + ((size_t)b0 * (NC * NR) + w) * NO + l4 * 4);

    #pragma unroll
    for (int j = 0; j < B_PER_BLOCK; ++j) {
        const f32x4 x0 = xp[0];
        const f32x4 x1 = xp[1];
        xp += (NR * NI) / 4;          // next b

        float u[4];
        #pragma unroll
        for (int k = 0; k < 4; ++k) {
            u[k] = wr[2*k].x   * x0.x + wr[2*k].y   * x0.y + wr[2*k].z   * x0.z + wr[2*k].w   * x0.w
                 + wr[2*k+1].x * x1.x + wr[2*k+1].y * x1.y + wr[2*k+1].z * x1.z + wr[2*k+1].w * x1.w;
        }

        // sq_norm over 16 o: 4 local + 2-step DPP butterfly across the 4-lane group
        float sq = u[0]*u[0] + u[1]*u[1] + u[2]*u[2] + u[3]*u[3];
        sq += dpp_quad<0xB1>(sq);     // quad_perm [1,0,3,2] : xor 1
        sq += dpp_quad<0x4E>(sq);     // quad_perm [2,3,0,1] : xor 2

        // factor = sq / ((1+sq) * sqrt(sq+1e-9)) via fast rcp/rsq
        const float f = sq * __builtin_amdgcn_rcpf(1.0f + sq)
                           * __builtin_amdgcn_rsqf(sq + 1e-9f);

        f32x4 v;
        v.x = u[0] * f; v.y = u[1] * f; v.z = u[2] * f; v.w = u[3] * f;
        __builtin_nontemporal_store(v, op);   // out lines never re-read: keep L2 for x/W
        op += (NC * NR * NO) / 4;     // next b
    }
}

extern "C" void kernel_launch(void* const* d_in, const int* in_sizes, int n_in,
                              void* d_out, int out_size, void* d_ws, size_t ws_size,
                              hipStream_t stream) {
    const float* x = (const float*)d_in[0];   // [256, 1152, 8]
    const float* W = (const float*)d_in[1];   // [1, 10, 1152, 16, 8]
    float* out = (float*)d_out;               // [256, 10, 1152, 16]

    dim3 grid(NC * NR / 64, NB / B_PER_BLOCK);  // (180, 16)
    dim3 block(256);
    capsule_squash_kernel<<<grid, block, 0, stream>>>(x, W, out);
}

// Round 5
// 39.296 us; speedup vs baseline: 2.0347x; 1.0507x over previous
//
#include <hip/hip_runtime.h>

// CapsuleLayer: u_hat[b,c,r,o] = sum_i W[c,r,o,i] * x[b,r,i]; out = squash(u_hat) over o.
// B=256, C=10, R=1152, I=8, O=16. fp32. Roofline: 188.7 MB write + ~15 MB fetch ≈ 30-32 us.
//
// Key change vs R4: x is staged into LDS once per block. Loads and stores share vmcnt on
// CDNA; with global x loads in the hot loop, every waitcnt before an FMA also forced older
// stores to retire (store-drain chained into the dep path). With x in LDS (lgkmcnt domain),
// the NT store stream is never waited on inside the loop.
// Hot-loop ds_read: 16 unique contiguous 16B addrs/wave = 2-way aliasing = free.

#define NB 256
#define NC 10
#define NR 1152
#define NI 8
#define NO 16
#define BPB 16            // batches per block
#define WPB 64            // (c,r) pairs per block

typedef float f32x4 __attribute__((ext_vector_type(4)));

template <int CTRL>
__device__ __forceinline__ float dpp_quad(float v) {
    int i = __builtin_bit_cast(int, v);
    int r = __builtin_amdgcn_update_dpp(i, i, CTRL, 0xF, 0xF, true);
    return __builtin_bit_cast(float, r);
}

__global__ __launch_bounds__(256, 5) void capsule_squash_kernel(
    const float* __restrict__ x,   // [B, R, I]
    const float* __restrict__ W,   // [C, R, O, I]
    float* __restrict__ out)       // [B, C, R, O]
{
    __shared__ float xs[BPB * WPB * NI];   // [16 b][64 r][8 i] = 32 KB, no pad (reads conflict-free)

    const int tid = threadIdx.x;
    const int w0  = blockIdx.x * WPB;      // 64-aligned; 1152/64=18 so a block never crosses c
    const int r0  = w0 % NR;
    const int b0  = blockIdx.y * BPB;

    // ---- stage x[b0+0..15, r0+0..63, 0..7] -> LDS (8 dwordx4 per thread) ----
    {
        const int bi    = tid >> 4;        // b-slice 0..15
        const int chunk = tid & 15;        // float4 column 0..15
        const f32x4* src = reinterpret_cast<const f32x4*>(x + ((size_t)(b0 + bi) * NR + r0) * NI);
        f32x4* dst = reinterpret_cast<f32x4*>(xs + bi * (WPB * NI));
        #pragma unroll
        for (int k = 0; k < 8; ++k)
            dst[chunk + 16 * k] = src[chunk + 16 * k];
    }

    // ---- this lane's 4 W rows (8 float4 = 32 VGPR), overlapped with staging ----
    const int l4 = tid & 3;                // lane's o = l4*4 + 0..3
    const int g  = tid >> 2;               // group 0..63
    const int w  = w0 + g;
    const f32x4* wp = reinterpret_cast<const f32x4*>(W + (size_t)(w * NO + l4 * 4) * NI);
    f32x4 wr[8];
    #pragma unroll
    for (int k = 0; k < 8; ++k) wr[k] = wp[k];

    __syncthreads();

    f32x4* op = reinterpret_cast<f32x4*>(out + ((size_t)b0 * (NC * NR) + w) * NO + l4 * 4);
    const f32x4* xrow = reinterpret_cast<const f32x4*>(xs) + g * 2;

    #pragma unroll
    for (int j = 0; j < BPB; ++j) {
        const f32x4 x0 = xrow[j * (WPB * NI / 4)];
        const f32x4 x1 = xrow[j * (WPB * NI / 4) + 1];

        float u[4];
        #pragma unroll
        for (int k = 0; k < 4; ++k) {
            u[k] = wr[2*k].x   * x0.x + wr[2*k].y   * x0.y + wr[2*k].z   * x0.z + wr[2*k].w   * x0.w
                 + wr[2*k+1].x * x1.x + wr[2*k+1].y * x1.y + wr[2*k+1].z * x1.z + wr[2*k+1].w * x1.w;
        }

        // sq_norm over 16 o: 4 local squares + 2-step DPP butterfly across the 4-lane group
        float sq = u[0]*u[0] + u[1]*u[1] + u[2]*u[2] + u[3]*u[3];
        sq += dpp_quad<0xB1>(sq);     // quad_perm [1,0,3,2] : xor 1
        sq += dpp_quad<0x4E>(sq);     // quad_perm [2,3,0,1] : xor 2

        // factor = sq / ((1+sq) * sqrt(sq+1e-9)) via fast rcp/rsq
        const float f = sq * __builtin_amdgcn_rcpf(1.0f + sq)
                           * __builtin_amdgcn_rsqf(sq + 1e-9f);

        f32x4 v;
        v.x = u[0] * f; v.y = u[1] * f; v.z = u[2] * f; v.w = u[3] * f;
        __builtin_nontemporal_store(v, op);   // out never re-read; vmcnt never waited in-loop
        op += (NC * NR * NO) / 4;             // next b
    }
}

extern "C" void kernel_launch(void* const* d_in, const int* in_sizes, int n_in,
                              void* d_out, int out_size, void* d_ws, size_t ws_size,
                              hipStream_t stream) {
    const float* x = (const float*)d_in[0];   // [256, 1152, 8]
    const float* W = (const float*)d_in[1];   // [1, 10, 1152, 16, 8]
    float* out = (float*)d_out;               // [256, 10, 1152, 16]

    dim3 grid(NC * NR / WPB, NB / BPB);       // (180, 16)
    dim3 block(256);
    capsule_squash_kernel<<<grid, block, 0, stream>>>(x, W, out);
}